// Round 10
// baseline (1846.560 us; speedup 1.0000x reference)
//
#include <hip/hip_runtime.h>
#include <hip/hip_bf16.h>

typedef __attribute__((ext_vector_type(8))) short bf16x8;
typedef __attribute__((ext_vector_type(4))) float f32x4;

#define L_SEQ 128
#define BATCH 64
#define HID   1024
#define GATES 4096
#define NXCD  8
#define BPX   8                     // batches per XCD
#define ROWS  16                    // padded batch rows per slot (rows 8-15 zero)
#define SLOT_U64 (ROWS * HID / 4)   // 4096 u64 per slot
#define CAN32 0x7FC17FC1u           // canary dword; |h|<1 bf16 can never be 0x7FC1
#define CAN64 0x7FC17FC17FC17FC1ull

__device__ inline short f2bf_s(float f) {
  __hip_bfloat16 h = __float2bfloat16(f);
  union { __hip_bfloat16 hh; short s; } u; u.hh = h; return u.s;
}
__device__ inline float sigm(float x) { return 1.f / (1.f + __expf(-x)); }
__device__ inline float tanh_f(float x) {
  x = fminf(x, 15.f);
  float e = __expf(2.f * x);
  return (e - 1.f) / (e + 1.f);
}
// reject if EITHER 4B half is canary -> torn stores respin, never accepted
__device__ inline bool is_can(unsigned long long q) {
  return ((unsigned)q == CAN32) | ((unsigned)(q >> 32) == CAN32);
}

// ---- init: x_bf, bias2, claim counters, h slots ([xcd][129][16][1024]) -----
// slot 0 rows 0-7 = hidden (per-XCD batches); slots 1..128 rows 0-7 = canary;
// rows 8-15 of ALL slots = zero (MFMA pad). System-UC stores put the data at
// the coherence point so k_scan's L2-miss fills see it, never stale bytes.
__global__ void k_init(const float* __restrict__ hidden, const float* __restrict__ x,
                       const float* __restrict__ bih, const float* __restrict__ bhh,
                       unsigned long long* __restrict__ h_all, __hip_bfloat16* __restrict__ x_bf,
                       float* __restrict__ bias2, int* __restrict__ claim) {
  int gid = blockIdx.x * 256 + threadIdx.x;            // 65536 threads
  if (gid < BATCH * 512) x_bf[gid] = __float2bfloat16(x[gid]);
  if (gid < GATES)       bias2[gid] = bih[gid] + bhh[gid];
  if (gid < NXCD)        claim[gid] = 0;
  const size_t TOT = (size_t)NXCD * (L_SEQ + 1) * SLOT_U64;   // 4,227,072 u64
  for (size_t i = gid; i < TOT; i += 65536) {
    size_t slotg = i >> 12;                 // global slot id (xcd*129 + t)
    int within = (int)(i & 4095);
    int b = within >> 8;                    // padded row 0..15
    int u4 = within & 255;                  // unit/4
    unsigned long long val;
    if (b >= BPX) val = 0ull;               // zero pad rows (all slots)
    else {
      int t = (int)(slotg % (L_SEQ + 1));
      if (t == 0) {
        int xcd = (int)(slotg / (L_SEQ + 1));
        const float* hp = hidden + ((size_t)(xcd * BPX + b)) * HID + u4 * 4;
        union { unsigned long long u; unsigned short s[4]; } p;
        p.s[0] = (unsigned short)f2bf_s(hp[0]); p.s[1] = (unsigned short)f2bf_s(hp[1]);
        p.s[2] = (unsigned short)f2bf_s(hp[2]); p.s[3] = (unsigned short)f2bf_s(hp[3]);
        val = p.u;
      } else val = CAN64;
    }
    __hip_atomic_store(&h_all[i], val, __ATOMIC_RELAXED, __HIP_MEMORY_SCOPE_SYSTEM);
  }
}

// ---- split W_ih into bf16 Wx (4096x512) and Wa (4096x512) ------------------
__global__ void k_wsplit(const float* __restrict__ Wih,
                         __hip_bfloat16* __restrict__ Wx, __hip_bfloat16* __restrict__ Wa) {
  int e = blockIdx.x * 256 + threadIdx.x;              // 4096*128
  int g = e >> 7;
  int ko = (e & 127) << 3;
  const float* src = Wih + (size_t)g * 1024 + ko;
  float4 f0 = *(const float4*)(src);
  float4 f1 = *(const float4*)(src + 4);
  union { bf16x8 v; short s[8]; } o;
  o.s[0]=f2bf_s(f0.x); o.s[1]=f2bf_s(f0.y); o.s[2]=f2bf_s(f0.z); o.s[3]=f2bf_s(f0.w);
  o.s[4]=f2bf_s(f1.x); o.s[5]=f2bf_s(f1.y); o.s[6]=f2bf_s(f1.z); o.s[7]=f2bf_s(f1.w);
  if (ko < 512) *(bf16x8*)(Wx + (size_t)g * 512 + ko)        = o.v;
  else          *(bf16x8*)(Wa + (size_t)g * 512 + (ko - 512)) = o.v;
}

// ---- W_hh -> fragment-major bf16 Whb ---------------------------------------
// Whb flat elem = (v*4 + gate)*16384 + kq*512 + lm*32 + quad*8 + e
// (v = u>>4, lm = u&15, kq = k>>5, quad = (k>>3)&3) — a wave's (tile,kq) read
// is 1024 contiguous bytes.
__global__ void k_wprep(const float* __restrict__ Whh, __hip_bfloat16* __restrict__ Whb) {
  int e = blockIdx.x * 256 + threadIdx.x;              // 2048 blocks -> 524288
  int row = e >> 7;                                    // gate*1024 + u
  int ko = (e & 127) << 3;
  int gate = row >> 10, u = row & 1023;
  int v = u >> 4, lm = u & 15, kq = ko >> 5, quad = (ko >> 3) & 3;
  const float* src = Whh + (size_t)row * HID + ko;
  float4 f0 = *(const float4*)(src);
  float4 f1 = *(const float4*)(src + 4);
  union { bf16x8 v8; short s[8]; } o;
  o.s[0]=f2bf_s(f0.x); o.s[1]=f2bf_s(f0.y); o.s[2]=f2bf_s(f0.z); o.s[3]=f2bf_s(f0.w);
  o.s[4]=f2bf_s(f1.x); o.s[5]=f2bf_s(f1.y); o.s[6]=f2bf_s(f1.z); o.s[7]=f2bf_s(f1.w);
  size_t dst = ((size_t)(v * 4 + gate)) * 16384 + kq * 512 + lm * 32 + quad * 8;
  *(bf16x8*)(Whb + dst) = o.v8;
}

// ---- act[l*64+b][512] = rule_emb[r]*v + tok_emb[t]*v (bf16) ----------------
__global__ void k_act(const int* __restrict__ pa, const float* __restrict__ remb,
                      const float* __restrict__ temb, __hip_bfloat16* __restrict__ act) {
  int row = blockIdx.x;                                // 8192 = l*64+b
  int tid = threadIdx.x;                               // 64
  int r  = pa[row * 3 + 0];
  int tk = pa[row * 3 + 1];
  float sr = (r  != -1) ? 1.f : 0.f; int ri = (r  != -1) ? r  : 0;
  float st = (tk != -1) ? 1.f : 0.f; int ti = (tk != -1) ? tk : 0;
  const float4* rr = (const float4*)(remb + (size_t)ri * 512);
  const float4* tr = (const float4*)(temb + (size_t)ti * 512);
  float4 a = rr[tid * 2], b4 = rr[tid * 2 + 1];
  float4 c4 = tr[tid * 2], d4 = tr[tid * 2 + 1];
  union { bf16x8 v; short s[8]; } o;
  o.s[0]=f2bf_s(sr*a.x + st*c4.x);  o.s[1]=f2bf_s(sr*a.y + st*c4.y);
  o.s[2]=f2bf_s(sr*a.z + st*c4.z);  o.s[3]=f2bf_s(sr*a.w + st*c4.w);
  o.s[4]=f2bf_s(sr*b4.x + st*d4.x); o.s[5]=f2bf_s(sr*b4.y + st*d4.y);
  o.s[6]=f2bf_s(sr*b4.z + st*d4.z); o.s[7]=f2bf_s(sr*b4.w + st*d4.w);
  *(bf16x8*)(act + (size_t)row * 512 + tid * 8) = o.v;
}

// ---- bf16 MFMA GEMM (unchanged, verified) ----------------------------------
template<int MODE>
__global__ __launch_bounds__(256) void k_gemm(
    const __hip_bfloat16* __restrict__ A, const __hip_bfloat16* __restrict__ B,
    const float* __restrict__ addend, float* __restrict__ Cf,
    __hip_bfloat16* __restrict__ Cb, int M) {
  __shared__ __hip_bfloat16 At[128][72];
  __shared__ __hip_bfloat16 Bt[128][72];
  const int tid = threadIdx.x;
  const int m0 = blockIdx.y * 128, n0 = blockIdx.x * 128;
  const int w = tid >> 6, lane = tid & 63;
  const int wm = (w >> 1) * 64, wn = (w & 1) * 64;
  const int lm = lane & 15, quad = lane >> 4;
  const int srow = tid >> 1, shalf = (tid & 1) * 32;
  f32x4 acc[4][4] = {};
  for (int k0 = 0; k0 < 512; k0 += 64) {
    int arow = m0 + srow;
    if (MODE == 0 && arow >= M) arow = M - 1;
    const bf16x8* ag = (const bf16x8*)(A + (size_t)arow * 512 + k0 + shalf);
    const bf16x8* bg = (const bf16x8*)(B + (size_t)(n0 + srow) * 512 + k0 + shalf);
    bf16x8 av[4], bv[4];
#pragma unroll
    for (int q = 0; q < 4; ++q) { av[q] = ag[q]; bv[q] = bg[q]; }
    __syncthreads();
#pragma unroll
    for (int q = 0; q < 4; ++q) {
      *(bf16x8*)(&At[srow][shalf + q * 8]) = av[q];
      *(bf16x8*)(&Bt[srow][shalf + q * 8]) = bv[q];
    }
    __syncthreads();
#pragma unroll
    for (int ks = 0; ks < 2; ++ks) {
      bf16x8 af[4], bf[4];
#pragma unroll
      for (int i = 0; i < 4; ++i) {
        af[i] = *(const bf16x8*)(&At[wm + i * 16 + lm][ks * 32 + quad * 8]);
        bf[i] = *(const bf16x8*)(&Bt[wn + i * 16 + lm][ks * 32 + quad * 8]);
      }
#pragma unroll
      for (int i = 0; i < 4; ++i)
#pragma unroll
        for (int j = 0; j < 4; ++j)
          acc[i][j] = __builtin_amdgcn_mfma_f32_16x16x32_bf16(af[i], bf[j], acc[i][j], 0, 0, 0);
    }
  }
#pragma unroll
  for (int i = 0; i < 4; ++i) {
    int mrow = m0 + wm + i * 16 + quad * 4;
#pragma unroll
    for (int j = 0; j < 4; ++j) {
      int ncol = n0 + wn + j * 16 + lm;
#pragma unroll
      for (int r = 0; r < 4; ++r) {
        int m = mrow + r;
        if (MODE == 0) {
          if (m < M) Cf[(size_t)m * GATES + ncol] = acc[i][j][r] + addend[ncol];
        } else {
          float v = acc[i][j][r] + addend[(size_t)(m & 63) * GATES + ncol];
          Cb[(size_t)m * GATES + ncol] = __float2bfloat16(v);
        }
      }
    }
  }
}

// ---- persistent LSTM scan: batch-split per XCD, intra-XCD L2 canary sync ---
// v15 = v14 hardened (round-9 container failure; kernel provably can't hang —
// every spin budgeted — so leading suspect was infra; risky constructs
// removed anyway): (1) inline-asm sc0 retry load (no early-clobber -> UB
// hazard) replaced with __hip_atomic_load AGENT (L1-bypass, well-defined);
// (2) publish via __hip_atomic_store AGENT (8B, non-tearing); (3) per-4B
// canary check. Design: XCD g owns batches [8g,8g+8) — ZERO cross-XCD
// communication; 32 WGs/XCD (rank = XCC_ID claim, replay-safe via &31) each
// own 32 hidden units; h exchange (16 KB/step) rides the XCD's coherent L2
// instead of the ~2us IC hops that floored v5-v13 at ~7us/step. W: 128 KB in
// LDS + 128 KB streamed from L2. Budgets everywhere: broken assumption ->
// fast absmax fail, never a hang.
__global__ __launch_bounds__(256, 1) void k_scan(
    const __hip_bfloat16* __restrict__ Whb, const __hip_bfloat16* __restrict__ xg,
    const float* __restrict__ state_in, unsigned long long* __restrict__ h_all,
    float* __restrict__ out_hs, float* __restrict__ out_hn, float* __restrict__ out_cn,
    int* __restrict__ claim) {
  __shared__ __hip_bfloat16 Wl[4 * 16384];             // 128 KB: [g][kq][lm][quad][8]
  __shared__ float glb[2][16][8][2];                   // gate g,o exchange
  __shared__ __align__(8) unsigned short hrep[2][8][16]; // h repack [pair][b][u']
  __shared__ int sxr;
  const int tid = threadIdx.x;
  unsigned xcc;
  asm volatile("s_getreg_b32 %0, hwreg(HW_REG_XCC_ID)" : "=s"(xcc));
  if (tid == 0) {
    int xcd = (int)(xcc & 7);
    int r = atomicAdd(&claim[xcd], 1);                 // device-scope, one-time
    sxr = (xcd << 8) | (r & 31);                       // &31: replay-safe ranks
  }
  __syncthreads();
  const int xcd = sxr >> 8, rank = sxr & 255;
  const int u0 = rank * 32;
  // LDS W: v-block 2*rank (units u0..u0+15, all 4 gates) — flat 128 KB copy
  {
    const bf16x8* src = (const bf16x8*)(Whb + (size_t)(2 * rank) * 4 * 16384);
    bf16x8* dst = (bf16x8*)Wl;
    for (int k = tid; k < 8192; k += 256) dst[k] = src[k];
  }
  const int wv = tid >> 6, lane = tid & 63;
  const int lm = lane & 15, quad = lane >> 4;
  const int pair = wv >> 1;        // 0: units u0+[0,16) from LDS; 1: u0+[16,32) streamed
  const int gsel = wv & 1;         // 0: gates i,f ; 1: gates g,o
  const __hip_bfloat16* Wg = Whb + (size_t)(2 * rank + 1) * 4 * 16384;  // streamed block
  const bool pw = (gsel == 0) && (quad < 2);           // pointwise-owner lanes
  float cc[4] = {0.f, 0.f, 0.f, 0.f};
  if (pw) {
#pragma unroll
    for (int r = 0; r < 4; ++r)
      cc[r] = state_in[(size_t)(xcd * BPX + quad * 4 + r) * HID + u0 + pair * 16 + lm];
  }
  unsigned long long* slotbase = h_all + (size_t)xcd * (L_SEQ + 1) * SLOT_U64;
  int budget = 1 << 21;                                // hang-proof spin budget
  __syncthreads();
  for (int t = 0; t < L_SEQ; ++t) {
    const unsigned long long* slotT = slotbase + (size_t)t * SLOT_U64;
    const unsigned long long* ab = slotT + (size_t)lm * 256 + quad * 2;  // row lm
    f32x4 acc0 = {0.f,0.f,0.f,0.f}, acc1 = {0.f,0.f,0.f,0.f};
    for (int kb = 0; kb < 4; ++kb) {
      union BF8 { bf16x8 v; unsigned long long q[2]; } a[8];
#pragma unroll
      for (int j = 0; j < 8; ++j)
        a[j].v = *(const bf16x8*)(ab + (size_t)(kb * 8 + j) * 8);   // fast-path load
      if (t > 0) {
#pragma unroll
        for (int j = 0; j < 8; ++j) {
          const unsigned long long* p0 = ab + (size_t)(kb * 8 + j) * 8;
          bool bad = is_can(a[j].q[0]) | is_can(a[j].q[1]);
          while (__any(bad)) {
            if (--budget < 0) break;
            __builtin_amdgcn_s_sleep(1);
            if (bad) {
              a[j].q[0] = __hip_atomic_load(p0,     __ATOMIC_RELAXED, __HIP_MEMORY_SCOPE_AGENT);
              a[j].q[1] = __hip_atomic_load(p0 + 1, __ATOMIC_RELAXED, __HIP_MEMORY_SCOPE_AGENT);
              bad = is_can(a[j].q[0]) | is_can(a[j].q[1]);
            }
          }
        }
      }
      if (pair == 0) {
#pragma unroll
        for (int j = 0; j < 8; ++j) {
          int kq = kb * 8 + j;
          bf16x8 w0 = *(const bf16x8*)(Wl + (size_t)(gsel * 2) * 16384 + kq * 512 + lm * 32 + quad * 8);
          bf16x8 w1 = *(const bf16x8*)(Wl + (size_t)(gsel * 2 + 1) * 16384 + kq * 512 + lm * 32 + quad * 8);
          acc0 = __builtin_amdgcn_mfma_f32_16x16x32_bf16(a[j].v, w0, acc0, 0, 0, 0);
          acc1 = __builtin_amdgcn_mfma_f32_16x16x32_bf16(a[j].v, w1, acc1, 0, 0, 0);
        }
      } else {
#pragma unroll
        for (int j = 0; j < 8; ++j) {
          int kq = kb * 8 + j;
          bf16x8 w0 = *(const bf16x8*)(Wg + (size_t)(gsel * 2) * 16384 + kq * 512 + lm * 32 + quad * 8);
          bf16x8 w1 = *(const bf16x8*)(Wg + (size_t)(gsel * 2 + 1) * 16384 + kq * 512 + lm * 32 + quad * 8);
          acc0 = __builtin_amdgcn_mfma_f32_16x16x32_bf16(a[j].v, w0, acc0, 0, 0, 0);
          acc1 = __builtin_amdgcn_mfma_f32_16x16x32_bf16(a[j].v, w1, acc1, 0, 0, 0);
        }
      }
    }
    // g,o accumulators -> pointwise waves
    if (gsel == 1 && quad < 2) {
#pragma unroll
      for (int r = 0; r < 4; ++r) {
        glb[pair][lm][quad * 4 + r][0] = acc0[r];      // gate g
        glb[pair][lm][quad * 4 + r][1] = acc1[r];      // gate o
      }
    }
    __syncthreads();
    if (pw) {
#pragma unroll
      for (int r = 0; r < 4; ++r) {
        int b = quad * 4 + r, gb = xcd * BPX + b, u = u0 + pair * 16 + lm;
        const __hip_bfloat16* xp = xg + ((size_t)t * BATCH + gb) * GATES + u;
        float xi  = __bfloat162float(xp[0]);
        float xf  = __bfloat162float(xp[1024]);
        float xgv = __bfloat162float(xp[2048]);
        float xo  = __bfloat162float(xp[3072]);
        float iv = sigm(acc0[r] + xi);
        float fv = sigm(acc1[r] + xf);
        float gv = tanh_f(glb[pair][lm][b][0] + xgv);
        float ov = sigm(glb[pair][lm][b][1] + xo);
        cc[r] = fv * cc[r] + iv * gv;
        float h = ov * tanh_f(cc[r]);
        __builtin_nontemporal_store(h, &out_hs[((size_t)t * BATCH + gb) * HID + u]);
        hrep[pair][b][lm] = (unsigned short)f2bf_s(h);
        if (t == L_SEQ - 1) {
          __builtin_nontemporal_store(h, &out_hn[(size_t)gb * HID + u]);
          __builtin_nontemporal_store(cc[r], &out_cn[(size_t)gb * HID + u]);
        }
      }
    }
    __syncthreads();
    // publish: 64 threads store this WG's 512 B into slot t+1 (AGENT -> L2)
    if (t < L_SEQ - 1 && tid < 64) {
      int p = tid >> 5, j = tid & 31, b = j >> 2, u4 = j & 3;
      unsigned long long q = ((const unsigned long long*)&hrep[p][b][0])[u4];
      unsigned long long* dst = slotbase + (size_t)(t + 1) * SLOT_U64
                              + (size_t)b * 256 + (u0 + p * 16) / 4 + u4;
      __hip_atomic_store(dst, q, __ATOMIC_RELAXED, __HIP_MEMORY_SCOPE_AGENT);
    }
    __syncthreads();                                   // hrep/glb reuse guard
  }
}

extern "C" void kernel_launch(void* const* d_in, const int* in_sizes, int n_in,
                              void* d_out, int out_size, void* d_ws, size_t ws_size,
                              hipStream_t stream) {
  const float* x      = (const float*)d_in[0];
  const int*   pa     = (const int*)d_in[1];
  // d_in[2] = mask (unused by reference)
  const float* hidden = (const float*)d_in[3];
  const float* state  = (const float*)d_in[4];
  const float* remb   = (const float*)d_in[5];
  const float* temb   = (const float*)d_in[6];
  const float* Wih    = (const float*)d_in[7];
  const float* Whh    = (const float*)d_in[8];
  const float* bih    = (const float*)d_in[9];
  const float* bhh    = (const float*)d_in[10];

  char* ws = (char*)d_ws;
  size_t off = 0;
  auto take = [&](size_t bytes) { char* p = ws + off; off += (bytes + 255) & ~(size_t)255; return p; };
  unsigned long long* h_all = (unsigned long long*)take((size_t)NXCD * (L_SEQ + 1) * SLOT_U64 * 8); // ~34 MB
  int* claim            = (int*)take(256);
  __hip_bfloat16* x_bf  = (__hip_bfloat16*)take((size_t)BATCH * 512 * 2);
  float* bias2          = (float*)take((size_t)GATES * 4);
  __hip_bfloat16* Wx    = (__hip_bfloat16*)take((size_t)GATES * 512 * 2);
  __hip_bfloat16* Wa    = (__hip_bfloat16*)take((size_t)GATES * 512 * 2);
  __hip_bfloat16* Whb   = (__hip_bfloat16*)take((size_t)GATES * HID * 2);   // 8 MB frag-major
  __hip_bfloat16* act   = (__hip_bfloat16*)take((size_t)8192 * 512 * 2);
  float* y0             = (float*)take((size_t)BATCH * GATES * 4);
  __hip_bfloat16* xg    = (__hip_bfloat16*)take((size_t)8192 * GATES * 2);  // 64 MB

  float* out_hs = (float*)d_out;
  float* out_hn = out_hs + (size_t)L_SEQ * BATCH * HID;
  float* out_cn = out_hn + (size_t)BATCH * HID;

  hipLaunchKernelGGL(k_init, dim3(256), dim3(256), 0, stream, hidden, x, bih, bhh, h_all, x_bf, bias2, claim);
  hipLaunchKernelGGL(k_wsplit, dim3(2048), dim3(256), 0, stream, Wih, Wx, Wa);
  hipLaunchKernelGGL(k_wprep, dim3(2048), dim3(256), 0, stream, Whh, Whb);
  hipLaunchKernelGGL(k_act, dim3(8192), dim3(64), 0, stream, pa, remb, temb, act);
  hipLaunchKernelGGL((k_gemm<0>), dim3(32, 1), dim3(256), 0, stream,
                     x_bf, Wx, bias2, y0, (__hip_bfloat16*)nullptr, 64);
  hipLaunchKernelGGL((k_gemm<1>), dim3(32, 64), dim3(256), 0, stream,
                     act, Wa, y0, (float*)nullptr, xg, 8192);
  hipLaunchKernelGGL(k_scan, dim3(256), dim3(256), 0, stream,
                     Whb, xg, state, h_all, out_hs, out_hn, out_cn, claim);
}